// Round 2
// baseline (720.916 us; speedup 1.0000x reference)
//
#include <hip/hip_runtime.h>
#include <cstddef>

// MonarchAttention fp32 implementation for MI355X.
// B=4,H=16 -> BH=64; N=4096, D=64, BLK b=64, m=64, STEPS=3, scale=1/8.
// Tile = one 64x64x64 matmul (+softmax) per workgroup of 256 threads.
//
// Workspace layout (needs 65 MB of d_ws):
//   S   = ws + 0        : 64 MB, time-shared:  L[bh][s][i][j]  (after K3)
//                                              qbar[bh][s][j][d] (after K1, same slice)
//                                              vbar stored at [bh][s][j][d] (K2-last column writes)
//                          step-0 compact qbar0[bh][s][d] lives in S[0..1MB)
//   ent = ws + 64MB     : 1 MB,  ent[bh][j][s]
// kbar[bh][j][s][d] lives in d_out (same slice set K3 reads is what it overwrites with out).

#define LP 68          // LDS row stride (floats): 16B-aligned float4 + bank spread
#define SCALE 0.125f

__device__ __forceinline__ float red16_max(float v){
#pragma unroll
  for (int m = 1; m < 16; m <<= 1) v = fmaxf(v, __shfl_xor(v, m, 64));
  return v;
}
__device__ __forceinline__ float red16_sum(float v){
#pragma unroll
  for (int m = 1; m < 16; m <<= 1) v += __shfl_xor(v, m, 64);
  return v;
}

// stage 64x64 row-major global -> LDS [r][c] with stride LP
__device__ __forceinline__ void stage_rm(float* __restrict__ dst, const float* __restrict__ src,
                                         int rowStride, int tid){
#pragma unroll
  for (int c = 0; c < 4; ++c){
    int lin = c * 256 + tid;
    int r = lin >> 4, c4 = (lin & 15) * 4;
    float4 v = *(const float4*)(src + (size_t)r * rowStride + c4);
    *(float4*)(dst + r * LP + c4) = v;
  }
}
// stage 64x64 row-major global -> transposed LDS [c][r] with stride LP
__device__ __forceinline__ void stage_tr(float* __restrict__ dstT, const float* __restrict__ src,
                                         int rowStride, int tid){
#pragma unroll
  for (int c = 0; c < 4; ++c){
    int lin = c * 256 + tid;
    int r = lin >> 4, c4 = (lin & 15) * 4;
    float4 v = *(const float4*)(src + (size_t)r * rowStride + c4);
    dstT[(c4 + 0) * LP + r] = v.x;
    dstT[(c4 + 1) * LP + r] = v.y;
    dstT[(c4 + 2) * LP + r] = v.z;
    dstT[(c4 + 3) * LP + r] = v.w;
  }
}

// C[64][64] += At^T * Bm where At,Bm are LDS [k][row]/[k][col], k=0..63.
// Thread (ty,tx) owns rows 4ty..4ty+3, cols 4tx..4tx+3.
__device__ __forceinline__ void mm64(const float* __restrict__ At, const float* __restrict__ Bm,
                                     float c[4][4], int ty4, int tx4){
#pragma unroll 8
  for (int k = 0; k < 64; ++k){
    float4 a = *(const float4*)(At + k * LP + ty4);
    float4 b = *(const float4*)(Bm + k * LP + tx4);
    c[0][0]=fmaf(a.x,b.x,c[0][0]); c[0][1]=fmaf(a.x,b.y,c[0][1]);
    c[0][2]=fmaf(a.x,b.z,c[0][2]); c[0][3]=fmaf(a.x,b.w,c[0][3]);
    c[1][0]=fmaf(a.y,b.x,c[1][0]); c[1][1]=fmaf(a.y,b.y,c[1][1]);
    c[1][2]=fmaf(a.y,b.z,c[1][2]); c[1][3]=fmaf(a.y,b.w,c[1][3]);
    c[2][0]=fmaf(a.z,b.x,c[2][0]); c[2][1]=fmaf(a.z,b.y,c[2][1]);
    c[2][2]=fmaf(a.z,b.z,c[2][2]); c[2][3]=fmaf(a.z,b.w,c[2][3]);
    c[3][0]=fmaf(a.w,b.x,c[3][0]); c[3][1]=fmaf(a.w,b.y,c[3][1]);
    c[3][2]=fmaf(a.w,b.z,c[3][2]); c[3][3]=fmaf(a.w,b.w,c[3][3]);
  }
}

// ---------------- step 0: qbar0[bh][s][d] = mean_i Q[bh][i*64+s][d]  (L uniform, w==1) ----
__global__ void __launch_bounds__(64) k_qbar0(const float* __restrict__ Q, float* __restrict__ qb0){
  int s = blockIdx.x, bh = blockIdx.y, d = threadIdx.x;
  const float* q = Q + (size_t)bh * 262144 + s * 64 + d;
  float acc = 0.f;
#pragma unroll 8
  for (int i = 0; i < 64; ++i) acc += q[(size_t)i * 4096];
  qb0[((size_t)bh * 64 + s) * 64 + d] = acc * (1.0f / 64.0f);
}

// ---------------- K1: qbar[bh][s][j][d] = (sum_i L[s][i][j] Q[i][s][d]) / w[j] -----------
// Reads L slice (bh,s) from S, overwrites the same slice with qbar.
__global__ void __launch_bounds__(256) k_qbar(const float* __restrict__ Q, float* __restrict__ S){
  __shared__ float Lt[64 * LP];   // L[i][j]
  __shared__ float Qt[64 * LP];   // Q[i][d]
  __shared__ float winv[64];
  int s = blockIdx.x, bh = blockIdx.y;
  int tid = threadIdx.x, tx4 = (tid & 15) * 4, ty4 = (tid >> 4) * 4;

  stage_rm(Lt, S + (size_t)(bh * 64 + s) * 4096, 64, tid);
  stage_rm(Qt, Q + (size_t)bh * 262144 + s * 64, 4096, tid);
  __syncthreads();

  if (tid < 64){
    float w = 0.f;
#pragma unroll 8
    for (int i = 0; i < 64; ++i) w += Lt[i * LP + tid];
    winv[tid] = 1.0f / w;
  }
  float c[4][4] = {};
  mm64(Lt, Qt, c, ty4, tx4);   // c[j][d]
  __syncthreads();             // winv ready; L slice fully consumed

  float* dst = S + (size_t)(bh * 64 + s) * 4096;
#pragma unroll
  for (int rr = 0; rr < 4; ++rr){
    float wi = winv[ty4 + rr];
    *(float4*)(dst + (ty4 + rr) * 64 + tx4) =
        make_float4(c[rr][0] * wi, c[rr][1] * wi, c[rr][2] * wi, c[rr][3] * wi);
  }
}

// ---------------- K2: R-softmax, kbar (+ ent; LAST also vbar) ----------------------------
template<bool STEP0, bool LAST>
__global__ void __launch_bounds__(256) k_R(const float* __restrict__ Kg, const float* __restrict__ Vg,
                                           float* __restrict__ S, float* __restrict__ kbar,
                                           float* __restrict__ ent){
  __shared__ float A0[64 * LP];  // qbT[d][s]  -> RT[t][s]
  __shared__ float A1[64 * LP];  // KT[d][t]   -> V[t][d] (LAST)
  __shared__ float A2[64 * LP];  // Krm[t][d]
  int j = blockIdx.x, bh = blockIdx.y;
  int tid = threadIdx.x, tx = tid & 15, tx4 = tx * 4, ty4 = (tid >> 4) * 4;

  // stage K once, into both layouts
  const float* Ksrc = Kg + (size_t)bh * 262144 + j * 4096;
#pragma unroll
  for (int cc = 0; cc < 4; ++cc){
    int lin = cc * 256 + tid;
    int r = lin >> 4, c4 = (lin & 15) * 4;
    float4 v = *(const float4*)(Ksrc + (size_t)r * 64 + c4);
    *(float4*)(A2 + r * LP + c4) = v;
    A1[(c4 + 0) * LP + r] = v.x; A1[(c4 + 1) * LP + r] = v.y;
    A1[(c4 + 2) * LP + r] = v.z; A1[(c4 + 3) * LP + r] = v.w;
  }
  const float* qsrc = STEP0 ? (S + (size_t)bh * 4096)            // qbar0[bh][s][d]
                            : (S + (size_t)bh * 262144 + j * 64); // qbar[bh][s][j][d], row stride 4096
  stage_tr(A0, qsrc, STEP0 ? 64 : 4096, tid);
  __syncthreads();

  float c[4][4] = {};
  mm64(A0, A1, c, ty4, tx4);    // scores[s][t] (unscaled)
  __syncthreads();              // A0/A1 reads complete -> safe to overwrite A0 with RT

  // row softmax over t (tx direction) + entropy; write RT[t][s] into A0
#pragma unroll
  for (int rr = 0; rr < 4; ++rr){
    float c0 = c[rr][0] * SCALE, c1 = c[rr][1] * SCALE, c2 = c[rr][2] * SCALE, c3 = c[rr][3] * SCALE;
    float M = red16_max(fmaxf(fmaxf(c0, c1), fmaxf(c2, c3)));
    float p0 = __expf(c0 - M), p1 = __expf(c1 - M), p2 = __expf(c2 - M), p3 = __expf(c3 - M);
    float sum = red16_sum(p0 + p1 + p2 + p3);
    float inv = 1.0f / sum, lse = __logf(sum);
    float r0 = p0 * inv, r1 = p1 * inv, r2 = p2 * inv, r3 = p3 * inv;
    float e = r0 * (c0 - M - lse) + r1 * (c1 - M - lse) + r2 * (c2 - M - lse) + r3 * (c3 - M - lse);
    e = red16_sum(e);
    int srow = ty4 + rr;
    if (tx == 0) ent[((size_t)bh * 64 + j) * 64 + srow] = -e;
    A0[(tx4 + 0) * LP + srow] = r0;
    A0[(tx4 + 1) * LP + srow] = r1;
    A0[(tx4 + 2) * LP + srow] = r2;
    A0[(tx4 + 3) * LP + srow] = r3;
  }
  __syncthreads();

  // kbar[s][d] = sum_t R[s][t] K[t][d]
  float c2r[4][4] = {};
  mm64(A0, A2, c2r, ty4, tx4);
  float* kdst = kbar + ((size_t)bh * 64 + j) * 4096;
#pragma unroll
  for (int rr = 0; rr < 4; ++rr)
    *(float4*)(kdst + (ty4 + rr) * 64 + tx4) =
        make_float4(c2r[rr][0], c2r[rr][1], c2r[rr][2], c2r[rr][3]);

  if (LAST){
    // stage V over KT (dead); A1's last read was pre-softmax sync
    stage_rm(A1, Vg + (size_t)bh * 262144 + j * 4096, 64, tid);
    __syncthreads();
    float c3r[4][4] = {};
    mm64(A0, A1, c3r, ty4, tx4);  // vbar[s][d]
    float* vdst = S + (size_t)bh * 262144 + j * 64;  // [bh][s][j][d]; this tile owns column j
#pragma unroll
    for (int rr = 0; rr < 4; ++rr)
      *(float4*)(vdst + (size_t)(ty4 + rr) * 4096 + tx4) =
          make_float4(c3r[rr][0], c3r[rr][1], c3r[rr][2], c3r[rr][3]);
  }
}

// ---------------- K3: L-softmax (non-last -> write L; last -> out = L·vbar) --------------
template<bool LAST>
__global__ void __launch_bounds__(256) k_L(const float* __restrict__ Qg, const float* __restrict__ kbar,
                                           const float* __restrict__ ent, float* __restrict__ S,
                                           float* __restrict__ outp){
  __shared__ float A0[64 * LP];  // QT[d][i] -> LT[j][i] (LAST)
  __shared__ float A1[64 * LP];  // kbT[d][j]
  __shared__ float A2[64 * LP];  // vbar[j][d] (LAST)
  __shared__ float entL[64];
  int s = blockIdx.x, bh = blockIdx.y;
  int tid = threadIdx.x, tx4 = (tid & 15) * 4, ty4 = (tid >> 4) * 4;

  stage_tr(A0, Qg + (size_t)bh * 262144 + s * 64, 4096, tid);    // Q[i][d] -> [d][i]
  stage_tr(A1, kbar + (size_t)bh * 262144 + s * 64, 4096, tid);  // kbar[j][d] -> [d][j]
  if (LAST) stage_rm(A2, S + (size_t)bh * 262144 + s * 4096, 64, tid);  // vbar rows j
  if (tid < 64) entL[tid] = ent[((size_t)bh * 64 + tid) * 64 + s];
  __syncthreads();

  float c[4][4] = {};
  mm64(A0, A1, c, ty4, tx4);    // scores_L[i][j] (unscaled, no ent yet)
  if (LAST) __syncthreads();    // A0 reads complete before LT overwrite

#pragma unroll
  for (int rr = 0; rr < 4; ++rr){
    float c0 = c[rr][0] * SCALE + entL[tx4 + 0];
    float c1 = c[rr][1] * SCALE + entL[tx4 + 1];
    float c2 = c[rr][2] * SCALE + entL[tx4 + 2];
    float c3 = c[rr][3] * SCALE + entL[tx4 + 3];
    float M = red16_max(fmaxf(fmaxf(c0, c1), fmaxf(c2, c3)));
    float p0 = __expf(c0 - M), p1 = __expf(c1 - M), p2 = __expf(c2 - M), p3 = __expf(c3 - M);
    float sum = red16_sum(p0 + p1 + p2 + p3);
    float inv = 1.0f / sum;
    float l0 = p0 * inv, l1 = p1 * inv, l2 = p2 * inv, l3 = p3 * inv;
    if (!LAST){
      *(float4*)(S + (size_t)(bh * 64 + s) * 4096 + (ty4 + rr) * 64 + tx4) =
          make_float4(l0, l1, l2, l3);
    } else {
      int irow = ty4 + rr;                 // LT[j][i]
      A0[(tx4 + 0) * LP + irow] = l0;
      A0[(tx4 + 1) * LP + irow] = l1;
      A0[(tx4 + 2) * LP + irow] = l2;
      A0[(tx4 + 3) * LP + irow] = l3;
    }
  }
  if (LAST){
    __syncthreads();
    float c2r[4][4] = {};
    mm64(A0, A2, c2r, ty4, tx4);  // out[i][d] = sum_j L[i][j] vbar[j][d]
    float* od = outp + (size_t)bh * 262144 + s * 64;  // out[bh][i*64+s][d]
#pragma unroll
    for (int rr = 0; rr < 4; ++rr)
      *(float4*)(od + (size_t)(ty4 + rr) * 4096 + tx4) =
          make_float4(c2r[rr][0], c2r[rr][1], c2r[rr][2], c2r[rr][3]);
  }
}

extern "C" void kernel_launch(void* const* d_in, const int* in_sizes, int n_in,
                              void* d_out, int out_size, void* d_ws, size_t ws_size,
                              hipStream_t stream) {
  const float* Q  = (const float*)d_in[0];
  const float* Kg = (const float*)d_in[1];
  const float* Vg = (const float*)d_in[2];
  float* out = (float*)d_out;            // doubles as kbar scratch between phases
  float* S   = (float*)d_ws;             // 64 MB shared L/qbar/vbar buffer
  float* ent = S + (size_t)16777216;     // +64 MB, 1 MB ent[bh][j][s]
  (void)in_sizes; (void)n_in; (void)out_size; (void)ws_size;

  dim3 g(64, 64), blk(256);

  // step 0
  k_qbar0<<<dim3(64, 64), 64, 0, stream>>>(Q, S);
  k_R<true,  false><<<g, blk, 0, stream>>>(Kg, Vg, S, out, ent);
  k_L<false><<<g, blk, 0, stream>>>(Q, out, ent, S, out);
  // step 1
  k_qbar<<<g, blk, 0, stream>>>(Q, S);
  k_R<false, false><<<g, blk, 0, stream>>>(Kg, Vg, S, out, ent);
  k_L<false><<<g, blk, 0, stream>>>(Q, out, ent, S, out);
  // step 2 (last)
  k_qbar<<<g, blk, 0, stream>>>(Q, S);
  k_R<false, true ><<<g, blk, 0, stream>>>(Kg, Vg, S, out, ent);
  k_L<true ><<<g, blk, 0, stream>>>(Q, out, ent, S, out);
}

// Round 3
// 562.317 us; speedup vs baseline: 1.2820x; 1.2820x over previous
//
#include <hip/hip_runtime.h>
#include <cstddef>

// MonarchAttention for MI355X — round 3: k_R / k_L matmuls on MFMA (bf16 hi/lo 3-term split).
// B=4,H=16 -> BH=64; N=4096, D=64, b=m=64, STEPS=3, scale=1/8.
//
// Workspace layout (65 MB of d_ws):
//   S   = ws + 0    : 64 MB time-shared: L[bh][s][i][j] / qbar[bh][s][j][d] / vbar[bh][s][j][d]
//                     step-0 compact qbar0[bh][s][d] in S[0..1MB)
//   ent = ws + 64MB : 1 MB ent[bh][j][s]
// kbar[bh][j][s][d] lives in d_out (k_L-last overwrites exactly the slice it stages).
//
// MFMA convention used (m89-verified C/D layout):
//   D[i][j] = sum_k A[i][k]B[k][j];  a-frag: A[l&15][(l>>4)*8+e];  b-frag: B[(l>>4)*8+e][l&15];
//   d: D[(l>>4)*4+r][l&15].  LDS operands row-major: A as [i][k], B as [j][k], stride LPB=72 bf16.

#define LP  68         // fp32 LDS stride (k_qbar path)
#define LPB 72         // bf16 LDS stride: 36 dwords -> 2-way (free) bank pattern on b128 frag reads
#define SCALE 0.125f

typedef __attribute__((ext_vector_type(8))) short bf16x8;
typedef __attribute__((ext_vector_type(4))) float f32x4;

__device__ __forceinline__ ushort f2bf(float x){
  uint u = __float_as_uint(x);
  u = (u + 0x7FFFu + ((u >> 16) & 1u)) >> 16;
  return (ushort)u;
}
__device__ __forceinline__ float bf2f(ushort h){ return __uint_as_float(((uint)h) << 16); }
__device__ __forceinline__ void split2(float x, ushort& h, ushort& l){
  h = f2bf(x); l = f2bf(x - bf2f(h));
}

__device__ __forceinline__ float red16_max(float v){
#pragma unroll
  for (int m = 1; m < 16; m <<= 1) v = fmaxf(v, __shfl_xor(v, m, 64));
  return v;
}
__device__ __forceinline__ float red16_sum(float v){
#pragma unroll
  for (int m = 1; m < 16; m <<= 1) v += __shfl_xor(v, m, 64);
  return v;
}

// ---- staging: 64x64 fp32 global -> bf16 hi/lo LDS ----
__device__ __forceinline__ void stage_rm_bf(ushort* __restrict__ H, ushort* __restrict__ L,
                                            const float* __restrict__ src, int rowStride, int tid){
#pragma unroll
  for (int c = 0; c < 4; ++c){
    int lin = c * 256 + tid, r = lin >> 4, c4 = (lin & 15) * 4;
    float4 v = *(const float4*)(src + (size_t)r * rowStride + c4);
    ushort4 h, l;
    split2(v.x, h.x, l.x); split2(v.y, h.y, l.y);
    split2(v.z, h.z, l.z); split2(v.w, h.w, l.w);
    *(ushort4*)(H + r * LPB + c4) = h;
    *(ushort4*)(L + r * LPB + c4) = l;
  }
}
__device__ __forceinline__ void stage_tr_bf(ushort* __restrict__ H, ushort* __restrict__ L,
                                            const float* __restrict__ src, int rowStride, int tid){
#pragma unroll
  for (int c = 0; c < 4; ++c){
    int lin = c * 256 + tid, r = lin >> 4, c4 = (lin & 15) * 4;
    float4 v = *(const float4*)(src + (size_t)r * rowStride + c4);
    ushort h, l;
    split2(v.x, h, l); H[(c4 + 0) * LPB + r] = h; L[(c4 + 0) * LPB + r] = l;
    split2(v.y, h, l); H[(c4 + 1) * LPB + r] = h; L[(c4 + 1) * LPB + r] = l;
    split2(v.z, h, l); H[(c4 + 2) * LPB + r] = h; L[(c4 + 2) * LPB + r] = l;
    split2(v.w, h, l); H[(c4 + 3) * LPB + r] = h; L[(c4 + 3) * LPB + r] = l;
  }
}

// ---- one 64x64x64 product, 3-term split, wave strip = 16 rows ----
__device__ __forceinline__ void gemm_tile(f32x4 acc[4],
                                          const ushort* __restrict__ AH, const ushort* __restrict__ AL,
                                          const ushort* __restrict__ BH, const ushort* __restrict__ BL,
                                          int aRow, int lm, int ko){
#pragma unroll
  for (int kb = 0; kb < 64; kb += 32){
    int k = kb + ko;
    bf16x8 ah = *(const bf16x8*)(AH + aRow * LPB + k);
    bf16x8 al = *(const bf16x8*)(AL + aRow * LPB + k);
#pragma unroll
    for (int ct = 0; ct < 4; ++ct){
      int br = ct * 16 + lm;
      bf16x8 bh = *(const bf16x8*)(BH + br * LPB + k);
      bf16x8 bl = *(const bf16x8*)(BL + br * LPB + k);
      acc[ct] = __builtin_amdgcn_mfma_f32_16x16x32_bf16(ah, bh, acc[ct], 0, 0, 0);
      acc[ct] = __builtin_amdgcn_mfma_f32_16x16x32_bf16(ah, bl, acc[ct], 0, 0, 0);
      acc[ct] = __builtin_amdgcn_mfma_f32_16x16x32_bf16(al, bh, acc[ct], 0, 0, 0);
    }
  }
}

// ---- fp32 helpers for the (unchanged) k_qbar path ----
__device__ __forceinline__ void stage_rm(float* __restrict__ dst, const float* __restrict__ src,
                                         int rowStride, int tid){
#pragma unroll
  for (int c = 0; c < 4; ++c){
    int lin = c * 256 + tid, r = lin >> 4, c4 = (lin & 15) * 4;
    float4 v = *(const float4*)(src + (size_t)r * rowStride + c4);
    *(float4*)(dst + r * LP + c4) = v;
  }
}
__device__ __forceinline__ void mm64(const float* __restrict__ At, const float* __restrict__ Bm,
                                     float c[4][4], int ty4, int tx4){
#pragma unroll 8
  for (int k = 0; k < 64; ++k){
    float4 a = *(const float4*)(At + k * LP + ty4);
    float4 b = *(const float4*)(Bm + k * LP + tx4);
    c[0][0]=fmaf(a.x,b.x,c[0][0]); c[0][1]=fmaf(a.x,b.y,c[0][1]);
    c[0][2]=fmaf(a.x,b.z,c[0][2]); c[0][3]=fmaf(a.x,b.w,c[0][3]);
    c[1][0]=fmaf(a.y,b.x,c[1][0]); c[1][1]=fmaf(a.y,b.y,c[1][1]);
    c[1][2]=fmaf(a.y,b.z,c[1][2]); c[1][3]=fmaf(a.y,b.w,c[1][3]);
    c[2][0]=fmaf(a.z,b.x,c[2][0]); c[2][1]=fmaf(a.z,b.y,c[2][1]);
    c[2][2]=fmaf(a.z,b.z,c[2][2]); c[2][3]=fmaf(a.z,b.w,c[2][3]);
    c[3][0]=fmaf(a.w,b.x,c[3][0]); c[3][1]=fmaf(a.w,b.y,c[3][1]);
    c[3][2]=fmaf(a.w,b.z,c[3][2]); c[3][3]=fmaf(a.w,b.w,c[3][3]);
  }
}

// ---------------- step 0: qbar0[bh][s][d] = mean_i Q[bh][i*64+s][d] ----------------------
__global__ void __launch_bounds__(64) k_qbar0(const float* __restrict__ Q, float* __restrict__ qb0){
  int s = blockIdx.x, bh = blockIdx.y, d = threadIdx.x;
  const float* q = Q + (size_t)bh * 262144 + s * 64 + d;
  float acc = 0.f;
#pragma unroll 8
  for (int i = 0; i < 64; ++i) acc += q[(size_t)i * 4096];
  qb0[((size_t)bh * 64 + s) * 64 + d] = acc * (1.0f / 64.0f);
}

// ---------------- K1: qbar (fp32 VALU path, unchanged) -----------------------------------
__global__ void __launch_bounds__(256) k_qbar(const float* __restrict__ Q, float* __restrict__ S){
  __shared__ float Lt[64 * LP];
  __shared__ float Qt[64 * LP];
  __shared__ float winv[64];
  int s = blockIdx.x, bh = blockIdx.y;
  int tid = threadIdx.x, tx4 = (tid & 15) * 4, ty4 = (tid >> 4) * 4;

  stage_rm(Lt, S + (size_t)(bh * 64 + s) * 4096, 64, tid);
  stage_rm(Qt, Q + (size_t)bh * 262144 + s * 64, 4096, tid);
  __syncthreads();

  if (tid < 64){
    float w = 0.f;
#pragma unroll 8
    for (int i = 0; i < 64; ++i) w += Lt[i * LP + tid];
    winv[tid] = 1.0f / w;
  }
  float c[4][4] = {};
  mm64(Lt, Qt, c, ty4, tx4);   // c[j][d]
  __syncthreads();

  float* dst = S + (size_t)(bh * 64 + s) * 4096;
#pragma unroll
  for (int rr = 0; rr < 4; ++rr){
    float wi = winv[ty4 + rr];
    *(float4*)(dst + (ty4 + rr) * 64 + tx4) =
        make_float4(c[rr][0] * wi, c[rr][1] * wi, c[rr][2] * wi, c[rr][3] * wi);
  }
}

// ---------------- K2: scores->R->kbar (+ent; LAST also vbar), MFMA -----------------------
template<bool STEP0, bool LAST>
__global__ void __launch_bounds__(256) k_R(const float* __restrict__ Kg, const float* __restrict__ Vg,
                                           float* __restrict__ S, float* __restrict__ kbar,
                                           float* __restrict__ ent){
  __shared__ alignas(16) ushort QH[64 * LPB], QL[64 * LPB];  // qbar rm [s][d]; LAST reuse: VT [d][t]
  __shared__ alignas(16) ushort KH[64 * LPB], KL[64 * LPB];  // K rm  [t][d]
  __shared__ alignas(16) ushort TH[64 * LPB], TL[64 * LPB];  // KT    [d][t]
  __shared__ alignas(16) ushort RH[64 * LPB], RL[64 * LPB];  // R rm  [s][t]
  int j = blockIdx.x, bh = blockIdx.y;
  int tid = threadIdx.x, lane = tid & 63;
  int lm = lane & 15, ko = (lane >> 4) * 8, g4 = (lane >> 4) * 4;
  int strip = 16 * (tid >> 6);

  // stage K once -> rm (KH/KL) + transposed (TH/TL)
  const float* Ksrc = Kg + (size_t)bh * 262144 + j * 4096;
#pragma unroll
  for (int c = 0; c < 4; ++c){
    int lin = c * 256 + tid, r = lin >> 4, c4 = (lin & 15) * 4;
    float4 v = *(const float4*)(Ksrc + (size_t)r * 64 + c4);
    ushort4 h, l;
    split2(v.x, h.x, l.x); split2(v.y, h.y, l.y);
    split2(v.z, h.z, l.z); split2(v.w, h.w, l.w);
    *(ushort4*)(KH + r * LPB + c4) = h;
    *(ushort4*)(KL + r * LPB + c4) = l;
    TH[(c4 + 0) * LPB + r] = h.x; TL[(c4 + 0) * LPB + r] = l.x;
    TH[(c4 + 1) * LPB + r] = h.y; TL[(c4 + 1) * LPB + r] = l.y;
    TH[(c4 + 2) * LPB + r] = h.z; TL[(c4 + 2) * LPB + r] = l.z;
    TH[(c4 + 3) * LPB + r] = h.w; TL[(c4 + 3) * LPB + r] = l.w;
  }
  const float* qsrc = STEP0 ? (S + (size_t)bh * 4096)             // qbar0[bh][s][d]
                            : (S + (size_t)bh * 262144 + j * 64); // qbar[bh][s][j][d]
  stage_rm_bf(QH, QL, qsrc, STEP0 ? 64 : 4096, tid);
  __syncthreads();

  // scores[s][t] = qbar . K^T   (A = qbar rm, B = K rm as [t][d])
  f32x4 acc[4] = {{0.f,0.f,0.f,0.f},{0.f,0.f,0.f,0.f},{0.f,0.f,0.f,0.f},{0.f,0.f,0.f,0.f}};
  gemm_tile(acc, QH, QL, KH, KL, strip + lm, lm, ko);

  // row softmax over t + entropy; write R hi/lo rm [s][t]
#pragma unroll
  for (int r = 0; r < 4; ++r){
    float c0 = acc[0][r] * SCALE, c1 = acc[1][r] * SCALE;
    float c2 = acc[2][r] * SCALE, c3 = acc[3][r] * SCALE;
    float M = red16_max(fmaxf(fmaxf(c0, c1), fmaxf(c2, c3)));
    float p0 = __expf(c0 - M), p1 = __expf(c1 - M), p2 = __expf(c2 - M), p3 = __expf(c3 - M);
    float sum = red16_sum(p0 + p1 + p2 + p3);
    float inv = 1.0f / sum, lse = __logf(sum);
    float r0 = p0 * inv, r1 = p1 * inv, r2 = p2 * inv, r3 = p3 * inv;
    float e = r0 * (c0 - M - lse) + r1 * (c1 - M - lse) + r2 * (c2 - M - lse) + r3 * (c3 - M - lse);
    e = red16_sum(e);
    int srow = strip + g4 + r;
    if (lm == 0) ent[((size_t)bh * 64 + j) * 64 + srow] = -e;
    ushort h, l;
    split2(r0, h, l); RH[srow * LPB +  0 + lm] = h; RL[srow * LPB +  0 + lm] = l;
    split2(r1, h, l); RH[srow * LPB + 16 + lm] = h; RL[srow * LPB + 16 + lm] = l;
    split2(r2, h, l); RH[srow * LPB + 32 + lm] = h; RL[srow * LPB + 32 + lm] = l;
    split2(r3, h, l); RH[srow * LPB + 48 + lm] = h; RL[srow * LPB + 48 + lm] = l;
  }
  __syncthreads();   // R ready; QH/QL & KH/KL fully consumed

  if (LAST)  // stage V transposed into QH/QL (dead); loads overlap kbar gemm below
    stage_tr_bf(QH, QL, Vg + (size_t)bh * 262144 + j * 4096, 64, tid);

  // kbar[s][d] = R . K   (A = R rm [s][t], B = KT as [d][t])
  f32x4 a2[4] = {{0.f,0.f,0.f,0.f},{0.f,0.f,0.f,0.f},{0.f,0.f,0.f,0.f},{0.f,0.f,0.f,0.f}};
  gemm_tile(a2, RH, RL, TH, TL, strip + lm, lm, ko);
  float* kdst = kbar + ((size_t)bh * 64 + j) * 4096;
#pragma unroll
  for (int ct = 0; ct < 4; ++ct)
#pragma unroll
    for (int r = 0; r < 4; ++r)
      kdst[(strip + g4 + r) * 64 + ct * 16 + lm] = a2[ct][r];

  if (LAST){
    __syncthreads();  // VT staged
    // vbar[s][d] = R . V   (A = R rm, B = VT as [d][t])
    f32x4 a3[4] = {{0.f,0.f,0.f,0.f},{0.f,0.f,0.f,0.f},{0.f,0.f,0.f,0.f},{0.f,0.f,0.f,0.f}};
    gemm_tile(a3, RH, RL, QH, QL, strip + lm, lm, ko);
    float* vdst = S + (size_t)bh * 262144 + j * 64;   // [bh][s][j][d], this block owns column j
#pragma unroll
    for (int ct = 0; ct < 4; ++ct)
#pragma unroll
      for (int r = 0; r < 4; ++r)
        vdst[(size_t)(strip + g4 + r) * 4096 + ct * 16 + lm] = a3[ct][r];
  }
}

// ---------------- K3: scores_L->L (non-last: write L; last: out = L.vbar), MFMA ----------
template<bool LAST>
__global__ void __launch_bounds__(256) k_L(const float* __restrict__ Qg, const float* __restrict__ kbar,
                                           const float* __restrict__ ent, float* __restrict__ S,
                                           float* __restrict__ outp){
  __shared__ alignas(16) ushort QH[64 * LPB], QL[64 * LPB];  // Q rm [i][d]; LAST reuse: L rm [i][j]
  __shared__ alignas(16) ushort BH[64 * LPB], BL[64 * LPB];  // kbar rm [j][d]; LAST reuse: VT [d][j]
  __shared__ float entL[64];
  int s = blockIdx.x, bh = blockIdx.y;
  int tid = threadIdx.x, lane = tid & 63;
  int lm = lane & 15, ko = (lane >> 4) * 8, g4 = (lane >> 4) * 4;
  int strip = 16 * (tid >> 6);

  stage_rm_bf(QH, QL, Qg + (size_t)bh * 262144 + s * 64, 4096, tid);
  stage_rm_bf(BH, BL, kbar + (size_t)bh * 262144 + s * 64, 4096, tid);
  if (tid < 64) entL[tid] = ent[((size_t)bh * 64 + tid) * 64 + s];
  __syncthreads();

  // scores_L[i][j] = Q . kbar^T   (A = Q rm, B = kbar rm as [j][d])
  f32x4 acc[4] = {{0.f,0.f,0.f,0.f},{0.f,0.f,0.f,0.f},{0.f,0.f,0.f,0.f},{0.f,0.f,0.f,0.f}};
  gemm_tile(acc, QH, QL, BH, BL, strip + lm, lm, ko);

  if (LAST){
    __syncthreads();  // all waves done reading QH/QL/BH/BL
    // stage vbar transposed into BH/BL; loads overlap the softmax below
    stage_tr_bf(BH, BL, S + (size_t)bh * 262144 + s * 4096, 64, tid);
  }

#pragma unroll
  for (int r = 0; r < 4; ++r){
    float c0 = acc[0][r] * SCALE + entL[ 0 + lm];
    float c1 = acc[1][r] * SCALE + entL[16 + lm];
    float c2 = acc[2][r] * SCALE + entL[32 + lm];
    float c3 = acc[3][r] * SCALE + entL[48 + lm];
    float M = red16_max(fmaxf(fmaxf(c0, c1), fmaxf(c2, c3)));
    float p0 = __expf(c0 - M), p1 = __expf(c1 - M), p2 = __expf(c2 - M), p3 = __expf(c3 - M);
    float sum = red16_sum(p0 + p1 + p2 + p3);
    float inv = 1.0f / sum;
    float l0 = p0 * inv, l1 = p1 * inv, l2 = p2 * inv, l3 = p3 * inv;
    int irow = strip + g4 + r;
    if (!LAST){
      float* dst = S + (size_t)(bh * 64 + s) * 4096 + irow * 64;
      dst[ 0 + lm] = l0; dst[16 + lm] = l1; dst[32 + lm] = l2; dst[48 + lm] = l3;
    } else {
      ushort h, l;
      split2(l0, h, l); QH[irow * LPB +  0 + lm] = h; QL[irow * LPB +  0 + lm] = l;
      split2(l1, h, l); QH[irow * LPB + 16 + lm] = h; QL[irow * LPB + 16 + lm] = l;
      split2(l2, h, l); QH[irow * LPB + 32 + lm] = h; QL[irow * LPB + 32 + lm] = l;
      split2(l3, h, l); QH[irow * LPB + 48 + lm] = h; QL[irow * LPB + 48 + lm] = l;
    }
  }
  if (LAST){
    __syncthreads();  // L + VT staged
    // out[i][d] = L . vbar   (A = L rm [i][j], B = VT as [d][j])
    f32x4 o[4] = {{0.f,0.f,0.f,0.f},{0.f,0.f,0.f,0.f},{0.f,0.f,0.f,0.f},{0.f,0.f,0.f,0.f}};
    gemm_tile(o, QH, QL, BH, BL, strip + lm, lm, ko);
    float* od = outp + (size_t)bh * 262144 + s * 64;   // out[bh][i*64+s][d]
#pragma unroll
    for (int ct = 0; ct < 4; ++ct)
#pragma unroll
      for (int r = 0; r < 4; ++r)
        od[(size_t)(strip + g4 + r) * 4096 + ct * 16 + lm] = o[ct][r];
  }
}

extern "C" void kernel_launch(void* const* d_in, const int* in_sizes, int n_in,
                              void* d_out, int out_size, void* d_ws, size_t ws_size,
                              hipStream_t stream) {
  const float* Q  = (const float*)d_in[0];
  const float* Kg = (const float*)d_in[1];
  const float* Vg = (const float*)d_in[2];
  float* out = (float*)d_out;            // doubles as kbar scratch between phases
  float* S   = (float*)d_ws;             // 64 MB shared L/qbar/vbar buffer
  float* ent = S + (size_t)16777216;     // +64 MB, 1 MB ent[bh][j][s]
  (void)in_sizes; (void)n_in; (void)out_size; (void)ws_size;

  dim3 g(64, 64), blk(256);

  // step 0
  k_qbar0<<<dim3(64, 64), 64, 0, stream>>>(Q, S);
  k_R<true,  false><<<g, blk, 0, stream>>>(Kg, Vg, S, out, ent);
  k_L<false><<<g, blk, 0, stream>>>(Q, out, ent, S, out);
  // step 1
  k_qbar<<<g, blk, 0, stream>>>(Q, S);
  k_R<false, false><<<g, blk, 0, stream>>>(Kg, Vg, S, out, ent);
  k_L<false><<<g, blk, 0, stream>>>(Q, out, ent, S, out);
  // step 2 (last)
  k_qbar<<<g, blk, 0, stream>>>(Q, S);
  k_R<false, true ><<<g, blk, 0, stream>>>(Kg, Vg, S, out, ent);
  k_L<true ><<<g, blk, 0, stream>>>(Q, out, ent, S, out);
}